// Round 15
// baseline (70.631 us; speedup 1.0000x reference)
//
#include <hip/hip_runtime.h>
#include <hip/hip_fp16.h>
#include <math.h>

constexpr int B    = 512;
constexpr int NIN  = 1024;
constexpr int NK   = 128;
constexpr int DK   = 5;
constexpr int NF   = NK * DK;     // 640 flattened kernel columns
constexpr int NOUT = NIN + NK;    // 1152
constexpr int SPLITK = 8;         // K chunks (128 each)
constexpr int LDA = 136;          // LDS row stride in halves (128 + 8 pad)
#define LOG2E 1.44269504088896f

typedef _Float16 f16x4 __attribute__((ext_vector_type(4)));
typedef _Float16 f16x8 __attribute__((ext_vector_type(8)));
typedef float    f32x4 __attribute__((ext_vector_type(4)));

// ---------------------------------------------------------------------------
// Kernel 1: split-K MFMA GEMM — byte-identical to R10/R14.
// ---------------------------------------------------------------------------
__global__ __launch_bounds__(256) void gemm_kernel(
        const float* __restrict__ x,       // [512][1024]
        const float* __restrict__ theta,   // [1024][640]
        __half* __restrict__ actvP16,      // [8][640][512]
        float* __restrict__ ps) {          // [8][640]
    __shared__ _Float16 Ath[32 * LDA];
    __shared__ _Float16 Bxh[64 * LDA];
    __shared__ float    red2[32][33];

    const int t    = threadIdx.x;
    const int tile = blockIdx.x >> 3;
    const int z    = blockIdx.x & 7;
    const int nt   = tile >> 3;
    const int bt   = tile & 7;
    const int n0   = nt * 32;
    const int b0   = bt * 64;
    const bool do_ps = (bt == 0);
    const int kw   = z * 128;

    const int kq = t >> 3;
    const int nc = (t & 7) * 4;
    float4 tv0 = *(const float4*)&theta[(kw + kq*4 + 0) * NF + n0 + nc];
    float4 tv1 = *(const float4*)&theta[(kw + kq*4 + 1) * NF + n0 + nc];
    float4 tv2 = *(const float4*)&theta[(kw + kq*4 + 2) * NF + n0 + nc];
    float4 tv3 = *(const float4*)&theta[(kw + kq*4 + 3) * NF + n0 + nc];

    const int br = t >> 2;
    const int ki = t & 3;
    float4 xv[8];
    #pragma unroll
    for (int i = 0; i < 8; ++i)
        xv[i] = *(const float4*)&x[(b0 + br) * NIN + kw + (ki + i * 4) * 4];

    if (do_ps) {
        red2[kq][nc + 0] = tv0.x*tv0.x + tv1.x*tv1.x + tv2.x*tv2.x + tv3.x*tv3.x;
        red2[kq][nc + 1] = tv0.y*tv0.y + tv1.y*tv1.y + tv2.y*tv2.y + tv3.y*tv3.y;
        red2[kq][nc + 2] = tv0.z*tv0.z + tv1.z*tv1.z + tv2.z*tv2.z + tv3.z*tv3.z;
        red2[kq][nc + 3] = tv0.w*tv0.w + tv1.w*tv1.w + tv2.w*tv2.w + tv3.w*tv3.w;
    }

    {
        f16x4 h;
        h[0]=(_Float16)tv0.x; h[1]=(_Float16)tv1.x; h[2]=(_Float16)tv2.x; h[3]=(_Float16)tv3.x;
        *(f16x4*)&Ath[(nc + 0) * LDA + kq * 4] = h;
        h[0]=(_Float16)tv0.y; h[1]=(_Float16)tv1.y; h[2]=(_Float16)tv2.y; h[3]=(_Float16)tv3.y;
        *(f16x4*)&Ath[(nc + 1) * LDA + kq * 4] = h;
        h[0]=(_Float16)tv0.z; h[1]=(_Float16)tv1.z; h[2]=(_Float16)tv2.z; h[3]=(_Float16)tv3.z;
        *(f16x4*)&Ath[(nc + 2) * LDA + kq * 4] = h;
        h[0]=(_Float16)tv0.w; h[1]=(_Float16)tv1.w; h[2]=(_Float16)tv2.w; h[3]=(_Float16)tv3.w;
        *(f16x4*)&Ath[(nc + 3) * LDA + kq * 4] = h;
    }
    #pragma unroll
    for (int i = 0; i < 8; ++i) {
        f16x4 h;
        h[0] = (_Float16)xv[i].x;  h[1] = (_Float16)xv[i].y;
        h[2] = (_Float16)xv[i].z;  h[3] = (_Float16)xv[i].w;
        *(f16x4*)&Bxh[br * LDA + (ki + i * 4) * 4] = h;
    }
    __syncthreads();

    const int w   = t >> 6;
    const int l   = t & 63;
    const int r16 = l & 15;
    const int kg  = l >> 4;

    f32x4 acc0 = {0.f,0.f,0.f,0.f}, acc1 = {0.f,0.f,0.f,0.f};
    #pragma unroll
    for (int ks = 0; ks < 4; ++ks) {
        const f16x8 bv  = *(const f16x8*)&Bxh[(w*16 + r16)*LDA + ks*32 + kg*8];
        const f16x8 av0 = *(const f16x8*)&Ath[( 0 + r16)*LDA + ks*32 + kg*8];
        const f16x8 av1 = *(const f16x8*)&Ath[(16 + r16)*LDA + ks*32 + kg*8];
        acc0 = __builtin_amdgcn_mfma_f32_16x16x32_f16(av0, bv, acc0, 0, 0, 0);
        acc1 = __builtin_amdgcn_mfma_f32_16x16x32_f16(av1, bv, acc1, 0, 0, 0);
    }

    {
        __half* dst = actvP16 + (size_t)z * NF * B
                    + (size_t)(n0 + kg*4) * B + b0 + w*16 + r16;
        #pragma unroll
        for (int j = 0; j < 4; ++j) {
            dst[j*B]          = __float2half(acc0[j]);
            dst[(16 + j) * B] = __float2half(acc1[j]);
        }
    }
    if (do_ps) {
        __syncthreads();
        if (t < 32) {
            float tot = 0.f;
            #pragma unroll
            for (int rr = 0; rr < 32; ++rr) tot += red2[rr][t];
            ps[z * NF + n0 + t] = tot;
        }
    }
}

// ---------------------------------------------------------------------------
// Kernel 2: pairwise — templated ablation (R14 body).
//   MODE 0: full (writes out)        — the real kernel
//   MODE 1: head only (stage+reduce+scale), live via scratch write
//   MODE 2: head + inner loop, exp replaced by fdot2 of the distance
// ---------------------------------------------------------------------------
template <int MODE>
__global__ __launch_bounds__(1024, 8) void pairwise_kernel(
        const __half* __restrict__ actvP16,// [8][640][512]
        const float* __restrict__ ps,      // [8][640]
        const float* __restrict__ lws,     // [640]
        const float* __restrict__ bias,    // [128]
        const float* __restrict__ x,       // [512][1024]
        float* __restrict__ out,           // [512][1152]
        float* __restrict__ scratch) {     // ablation sink
    __shared__ __half a16s[DK * B];
    __shared__ float  red[8 * 128];
    __shared__ float  s_sh[DK];
    __shared__ float  red_ps[DK * SPLITK];

    const int k = blockIdx.x;
    const int e = blockIdx.y;
    const int t = threadIdx.x;

    if (t >= 512 && t < 768) {
        const int u = t - 512;
        const int row = k * 4 + e;
        ((float4*)out)[row * (NOUT/4) + u] = ((const float4*)x)[row * (NIN/4) + u];
    }
    if (t >= 768 && t < 768 + DK * SPLITK) {
        const int u = t - 768;
        red_ps[u] = ps[(u / DK) * NF + k * DK + (u % DK)];
    }

    const size_t slab = (size_t)k * DK * B;
    float accf[8];
    #pragma unroll
    for (int i = 0; i < 8; ++i) accf[i] = 0.f;
    if (t < 320) {
        #pragma unroll
        for (int z = 0; z < SPLITK; ++z) {
            const f16x8 v = *(const f16x8*)(actvP16 + (size_t)z * NF * B + slab + t * 8);
            #pragma unroll
            for (int i = 0; i < 8; ++i) accf[i] += (float)v[i];
        }
    }
    __syncthreads();
    if (t < DK) {
        float sum = 0.f;
        #pragma unroll
        for (int c = 0; c < SPLITK; ++c) sum += red_ps[c * DK + t];
        s_sh[t] = __expf(lws[k * DK + t]) * rsqrtf(sum) * LOG2E;
    }
    __syncthreads();
    if (t < 320) {
        const float s = s_sh[t >> 6];
        f16x8 h;
        #pragma unroll
        for (int i = 0; i < 8; ++i) h[i] = (_Float16)(accf[i] * s);
        *(f16x8*)&a16s[t * 8] = h;
    }
    __syncthreads();

    if constexpr (MODE == 1) {
        // keep the entire head live; skip the loop
        if (t < 320)
            scratch[((e * NK) + k) * 320 + t] = __half2float(a16s[t * 8]);
        return;
    }

    const int g  = t >> 7;
    const int r  = t & 127;
    const int ba = e * 128 + r;

    __half2 A2[DK];
    #pragma unroll
    for (int d = 0; d < DK; ++d) A2[d] = __half2half2(a16s[d * B + ba]);

    float acc = 0.f;
    const int bp0 = g * 64;

    union W8 { f16x8 v; __half2 h[4]; };
    typedef _Float16 f16x2v __attribute__((ext_vector_type(2)));
    union HV { __half2 h; f16x2v v; };
    const HV ones = {__half2half2(__float2half(1.0f))};

    #pragma unroll 2
    for (int m = 0; m < 8; ++m) {
        const int bp = bp0 + m * 8;
        W8 w0, w1, w2, w3, w4;
        w0.v = *(const f16x8*)&a16s[0*B + bp];
        w1.v = *(const f16x8*)&a16s[1*B + bp];
        w2.v = *(const f16x8*)&a16s[2*B + bp];
        w3.v = *(const f16x8*)&a16s[3*B + bp];
        w4.v = *(const f16x8*)&a16s[4*B + bp];
        #pragma unroll
        for (int c = 0; c < 4; ++c) {
            __half2 dA = __habs2(__hsub2(A2[0], w0.h[c]));
            dA = __hadd2(dA, __habs2(__hsub2(A2[1], w1.h[c])));
            dA = __hadd2(dA, __habs2(__hsub2(A2[2], w2.h[c])));
            dA = __hadd2(dA, __habs2(__hsub2(A2[3], w3.h[c])));
            dA = __hadd2(dA, __habs2(__hsub2(A2[4], w4.h[c])));
            if constexpr (MODE == 2) {
                // distance kept live; trans pipe removed
                HV u; u.h = dA;
#if __has_builtin(__builtin_amdgcn_fdot2)
                acc = __builtin_amdgcn_fdot2(u.v, ones.v, acc, false);
#else
                acc += __low2float(u.h) + __high2float(u.h);
#endif
            } else {
                HV eA; eA.h = h2exp2(__hneg2(dA));
#if __has_builtin(__builtin_amdgcn_fdot2)
                acc = __builtin_amdgcn_fdot2(eA.v, ones.v, acc, false);
#else
                acc += __low2float(eA.h) + __high2float(eA.h);
#endif
            }
        }
    }
    red[g * 128 + r] = acc;
    __syncthreads();
    if (t < 128) {
        float f = -1.0f + bias[k];
        #pragma unroll
        for (int gg = 0; gg < 8; ++gg) f += red[gg * 128 + t];
        if constexpr (MODE == 0)
            out[(e * 128 + t) * NOUT + NIN + k] = f;
        else
            scratch[((e * NK) + k) * 128 + t] = f;
    }
}

// ---------------------------------------------------------------------------
extern "C" void kernel_launch(void* const* d_in, const int* in_sizes, int n_in,
                              void* d_out, int out_size, void* d_ws, size_t ws_size,
                              hipStream_t stream) {
    const float* x     = (const float*)d_in[0];
    const float* theta = (const float*)d_in[1];
    const float* lws   = (const float*)d_in[2];
    const float* bias  = (const float*)d_in[3];
    float* out = (float*)d_out;

    // ws: ps @0 (64KB), actvP16 @64KB (5.24MB), scratch @8MB (~0.7MB)
    char* wsb = (char*)d_ws;
    float*  ps       = (float*)wsb;
    __half* actvP16  = (__half*)(wsb + (64 << 10));
    float*  scratch  = (float*)(wsb + (8u << 20));

    gemm_kernel<<<dim3(1280), 256, 0, stream>>>(x, theta, actvP16, ps);
    // ---- amplified ablation: 3x head-only, 3x no-exp, then the real one ----
    pairwise_kernel<1><<<dim3(NK, 4), 1024, 0, stream>>>(actvP16, ps, lws, bias, x, out, scratch);
    pairwise_kernel<1><<<dim3(NK, 4), 1024, 0, stream>>>(actvP16, ps, lws, bias, x, out, scratch);
    pairwise_kernel<1><<<dim3(NK, 4), 1024, 0, stream>>>(actvP16, ps, lws, bias, x, out, scratch);
    pairwise_kernel<2><<<dim3(NK, 4), 1024, 0, stream>>>(actvP16, ps, lws, bias, x, out, scratch);
    pairwise_kernel<2><<<dim3(NK, 4), 1024, 0, stream>>>(actvP16, ps, lws, bias, x, out, scratch);
    pairwise_kernel<2><<<dim3(NK, 4), 1024, 0, stream>>>(actvP16, ps, lws, bias, x, out, scratch);
    pairwise_kernel<0><<<dim3(NK, 4), 1024, 0, stream>>>(actvP16, ps, lws, bias, x, out, scratch);
}

// Round 16
// 24.629 us; speedup vs baseline: 2.8678x; 2.8678x over previous
//
#include <hip/hip_runtime.h>
#include <hip/hip_fp16.h>
#include <math.h>

constexpr int B    = 512;
constexpr int NIN  = 1024;
constexpr int NK   = 128;
constexpr int DK   = 5;
constexpr int NF   = NK * DK;     // 640 flattened kernel columns
constexpr int NOUT = NIN + NK;    // 1152
constexpr int SPLITK = 8;         // K chunks (128 each)
constexpr int LDA = 136;          // LDS row stride in halves (128 + 8 pad)
#define LOG2E 1.44269504088896f

typedef _Float16 f16x4 __attribute__((ext_vector_type(4)));
typedef _Float16 f16x8 __attribute__((ext_vector_type(8)));
typedef float    f32x4 __attribute__((ext_vector_type(4)));

// ---------------------------------------------------------------------------
// Kernel 1: split-K MFMA GEMM — byte-identical to R10/R14.
// ---------------------------------------------------------------------------
__global__ __launch_bounds__(256) void gemm_kernel(
        const float* __restrict__ x,       // [512][1024]
        const float* __restrict__ theta,   // [1024][640]
        __half* __restrict__ actvP16,      // [8][640][512]
        float* __restrict__ ps) {          // [8][640]
    __shared__ _Float16 Ath[32 * LDA];
    __shared__ _Float16 Bxh[64 * LDA];
    __shared__ float    red2[32][33];

    const int t    = threadIdx.x;
    const int tile = blockIdx.x >> 3;
    const int z    = blockIdx.x & 7;
    const int nt   = tile >> 3;
    const int bt   = tile & 7;
    const int n0   = nt * 32;
    const int b0   = bt * 64;
    const bool do_ps = (bt == 0);
    const int kw   = z * 128;

    const int kq = t >> 3;
    const int nc = (t & 7) * 4;
    float4 tv0 = *(const float4*)&theta[(kw + kq*4 + 0) * NF + n0 + nc];
    float4 tv1 = *(const float4*)&theta[(kw + kq*4 + 1) * NF + n0 + nc];
    float4 tv2 = *(const float4*)&theta[(kw + kq*4 + 2) * NF + n0 + nc];
    float4 tv3 = *(const float4*)&theta[(kw + kq*4 + 3) * NF + n0 + nc];

    const int br = t >> 2;
    const int ki = t & 3;
    float4 xv[8];
    #pragma unroll
    for (int i = 0; i < 8; ++i)
        xv[i] = *(const float4*)&x[(b0 + br) * NIN + kw + (ki + i * 4) * 4];

    if (do_ps) {
        red2[kq][nc + 0] = tv0.x*tv0.x + tv1.x*tv1.x + tv2.x*tv2.x + tv3.x*tv3.x;
        red2[kq][nc + 1] = tv0.y*tv0.y + tv1.y*tv1.y + tv2.y*tv2.y + tv3.y*tv3.y;
        red2[kq][nc + 2] = tv0.z*tv0.z + tv1.z*tv1.z + tv2.z*tv2.z + tv3.z*tv3.z;
        red2[kq][nc + 3] = tv0.w*tv0.w + tv1.w*tv1.w + tv2.w*tv2.w + tv3.w*tv3.w;
    }

    {
        f16x4 h;
        h[0]=(_Float16)tv0.x; h[1]=(_Float16)tv1.x; h[2]=(_Float16)tv2.x; h[3]=(_Float16)tv3.x;
        *(f16x4*)&Ath[(nc + 0) * LDA + kq * 4] = h;
        h[0]=(_Float16)tv0.y; h[1]=(_Float16)tv1.y; h[2]=(_Float16)tv2.y; h[3]=(_Float16)tv3.y;
        *(f16x4*)&Ath[(nc + 1) * LDA + kq * 4] = h;
        h[0]=(_Float16)tv0.z; h[1]=(_Float16)tv1.z; h[2]=(_Float16)tv2.z; h[3]=(_Float16)tv3.z;
        *(f16x4*)&Ath[(nc + 2) * LDA + kq * 4] = h;
        h[0]=(_Float16)tv0.w; h[1]=(_Float16)tv1.w; h[2]=(_Float16)tv2.w; h[3]=(_Float16)tv3.w;
        *(f16x4*)&Ath[(nc + 3) * LDA + kq * 4] = h;
    }
    #pragma unroll
    for (int i = 0; i < 8; ++i) {
        f16x4 h;
        h[0] = (_Float16)xv[i].x;  h[1] = (_Float16)xv[i].y;
        h[2] = (_Float16)xv[i].z;  h[3] = (_Float16)xv[i].w;
        *(f16x4*)&Bxh[br * LDA + (ki + i * 4) * 4] = h;
    }
    __syncthreads();

    const int w   = t >> 6;
    const int l   = t & 63;
    const int r16 = l & 15;
    const int kg  = l >> 4;

    f32x4 acc0 = {0.f,0.f,0.f,0.f}, acc1 = {0.f,0.f,0.f,0.f};
    #pragma unroll
    for (int ks = 0; ks < 4; ++ks) {
        const f16x8 bv  = *(const f16x8*)&Bxh[(w*16 + r16)*LDA + ks*32 + kg*8];
        const f16x8 av0 = *(const f16x8*)&Ath[( 0 + r16)*LDA + ks*32 + kg*8];
        const f16x8 av1 = *(const f16x8*)&Ath[(16 + r16)*LDA + ks*32 + kg*8];
        acc0 = __builtin_amdgcn_mfma_f32_16x16x32_f16(av0, bv, acc0, 0, 0, 0);
        acc1 = __builtin_amdgcn_mfma_f32_16x16x32_f16(av1, bv, acc1, 0, 0, 0);
    }

    {
        __half* dst = actvP16 + (size_t)z * NF * B
                    + (size_t)(n0 + kg*4) * B + b0 + w*16 + r16;
        #pragma unroll
        for (int j = 0; j < 4; ++j) {
            dst[j*B]          = __float2half(acc0[j]);
            dst[(16 + j) * B] = __float2half(acc1[j]);
        }
    }
    if (do_ps) {
        __syncthreads();
        if (t < 32) {
            float tot = 0.f;
            #pragma unroll
            for (int rr = 0; rr < 32; ++rr) tot += red2[rr][t];
            ps[z * NF + n0 + t] = tot;
        }
    }
}

// ---------------------------------------------------------------------------
// Kernel 2: pairwise — 4 rows/thread (4x fewer LDS wave-reads), f32 exp path.
// grid (128 k, 2 e) x 1024 thr, launch_bounds(1024, 4).
//   wave w (0..15) owns b' strip w*32..+31 (wave-uniform -> LDS broadcast);
//   lane l owns rows e*256 + l*4 .. +3.
// ---------------------------------------------------------------------------
__global__ __launch_bounds__(1024, 4) void pairwise_kernel(
        const __half* __restrict__ actvP16,// [8][640][512]
        const float* __restrict__ ps,      // [8][640]
        const float* __restrict__ lws,     // [640]
        const float* __restrict__ bias,    // [128]
        const float* __restrict__ x,       // [512][1024]
        float* __restrict__ out) {         // [512][1152]
    __shared__ __half a16s[DK * B];        // 5120 B
    __shared__ float  red[16 * 256];       // 16 KB
    __shared__ float  s_sh[DK];
    __shared__ float  red_ps[DK * SPLITK];

    const int k = blockIdx.x;
    const int e = blockIdx.y;              // b-half (0..1)
    const int t = threadIdx.x;

    // fused x passthrough: threads [512,1024) copy rows k*4+e*2, +1
    if (t >= 512) {
        const int u = t - 512;             // 0..511 = 2 rows x 256 float4
        const int row = k * 4 + e * 2 + (u >> 8);
        const int c4  = u & 255;
        ((float4*)out)[row * (NOUT/4) + c4] = ((const float4*)x)[row * (NIN/4) + c4];
    }
    if (t >= 320 && t < 320 + DK * SPLITK) {
        const int u = t - 320;
        red_ps[u] = ps[(u / DK) * NF + k * DK + (u % DK)];
    }

    // ---- split-K reduce into f32 regs: unit t = 8 halves (t < 320) ----
    const size_t slab = (size_t)k * DK * B;
    float accf[8];
    #pragma unroll
    for (int i = 0; i < 8; ++i) accf[i] = 0.f;
    if (t < 320) {
        #pragma unroll
        for (int z = 0; z < SPLITK; ++z) {
            const f16x8 v = *(const f16x8*)(actvP16 + (size_t)z * NF * B + slab + t * 8);
            #pragma unroll
            for (int i = 0; i < 8; ++i) accf[i] += (float)v[i];
        }
    }
    __syncthreads();
    if (t < DK) {
        float sum = 0.f;
        #pragma unroll
        for (int c = 0; c < SPLITK; ++c) sum += red_ps[c * DK + t];
        s_sh[t] = __expf(lws[k * DK + t]) * rsqrtf(sum) * LOG2E;
    }
    __syncthreads();
    if (t < 320) {
        const float s = s_sh[t >> 6];
        f16x8 h;
        #pragma unroll
        for (int i = 0; i < 8; ++i) h[i] = (_Float16)(accf[i] * s);
        *(f16x8*)&a16s[t * 8] = h;
    }
    __syncthreads();

    // ---- inner loop: 4 rows x 32 b' per thread ----
    const int w  = t >> 6;                 // wave id -> b' strip (uniform)
    const int l  = t & 63;
    const int ba = e * 256 + l * 4;        // 4 consecutive rows

    __half2 A2[4][DK];
    #pragma unroll
    for (int j = 0; j < 4; ++j)
        #pragma unroll
        for (int d = 0; d < DK; ++d)
            A2[j][d] = __half2half2(a16s[d * B + ba + j]);

    float acc[4] = {0.f, 0.f, 0.f, 0.f};
    const int bp0 = w * 32;

    union W8 { f16x8 v; __half2 h[4]; };
    #pragma unroll
    for (int m = 0; m < 4; ++m) {
        const int bp = bp0 + m * 8;        // wave-uniform -> LDS b128 broadcast
        W8 w0, w1, w2, w3, w4;
        w0.v = *(const f16x8*)&a16s[0*B + bp];
        w1.v = *(const f16x8*)&a16s[1*B + bp];
        w2.v = *(const f16x8*)&a16s[2*B + bp];
        w3.v = *(const f16x8*)&a16s[3*B + bp];
        w4.v = *(const f16x8*)&a16s[4*B + bp];
        #pragma unroll
        for (int c = 0; c < 4; ++c) {
            #pragma unroll
            for (int j = 0; j < 4; ++j) {
                __half2 dA = __habs2(__hsub2(A2[j][0], w0.h[c]));
                dA = __hadd2(dA, __habs2(__hsub2(A2[j][1], w1.h[c])));
                dA = __hadd2(dA, __habs2(__hsub2(A2[j][2], w2.h[c])));
                dA = __hadd2(dA, __habs2(__hsub2(A2[j][3], w3.h[c])));
                dA = __hadd2(dA, __habs2(__hsub2(A2[j][4], w4.h[c])));
                const float lo = __low2float(dA);
                const float hi = __high2float(dA);
                acc[j] += __builtin_amdgcn_exp2f(-lo);
                acc[j] += __builtin_amdgcn_exp2f(-hi);
            }
        }
    }
    #pragma unroll
    for (int j = 0; j < 4; ++j)
        red[w * 256 + (l * 4 + j)] = acc[j];
    __syncthreads();

    if (t < 256) {
        float f = -1.0f + bias[k];
        #pragma unroll
        for (int gg = 0; gg < 16; ++gg) f += red[gg * 256 + t];
        out[(size_t)(e * 256 + t) * NOUT + NIN + k] = f;
    }
}

// ---------------------------------------------------------------------------
extern "C" void kernel_launch(void* const* d_in, const int* in_sizes, int n_in,
                              void* d_out, int out_size, void* d_ws, size_t ws_size,
                              hipStream_t stream) {
    const float* x     = (const float*)d_in[0];   // [512,1024]
    const float* theta = (const float*)d_in[1];   // [1024,128,5]
    const float* lws   = (const float*)d_in[2];   // [128,5]
    const float* bias  = (const float*)d_in[3];   // [128]
    float* out = (float*)d_out;                   // [512,1152]

    // ws layout: ps @0 (64KB pad), actvP16 f16 8 slabs @64KB (5.24MB)
    char* wsb = (char*)d_ws;
    float*  ps       = (float*)wsb;
    __half* actvP16  = (__half*)(wsb + (64 << 10));

    gemm_kernel<<<dim3(1280), 256, 0, stream>>>(x, theta, actvP16, ps);
    pairwise_kernel<<<dim3(NK, 2), 1024, 0, stream>>>(actvP16, ps, lws, bias, x, out);
}